// Round 4
// baseline (514.050 us; speedup 1.0000x reference)
//
#include <hip/hip_runtime.h>
#include <hip/hip_bf16.h>
#include <cstdint>

#define D_MODEL 1024
#define SEQ     2048
#define SCALE   0.125f
#define P_ELEMS 2228224   // per-batch packed triangular elems: 16384*136

typedef __attribute__((ext_vector_type(8))) _Float16 f16x8;
typedef __attribute__((ext_vector_type(8))) unsigned short u16x8;
typedef __attribute__((ext_vector_type(4))) unsigned short u16x4;
typedef __attribute__((ext_vector_type(4))) float f32x4;

__device__ __forceinline__ unsigned short f2h(float f) {
  _Float16 h = (_Float16)f;
  return __builtin_bit_cast(unsigned short, h);
}
__device__ __forceinline__ float h2f(unsigned short u) {
  return (float)__builtin_bit_cast(_Float16, u);
}

// ---- kernel 1: x f32 -> f16 ----
__global__ __launch_bounds__(256) void cvt_x(const float* __restrict__ x,
                                             unsigned short* __restrict__ o, int n8) {
  int i = blockIdx.x * 256 + threadIdx.x;
  if (i >= n8) return;
  const float4* p = (const float4*)x + (size_t)i * 2;
  float4 a = p[0], b = p[1];
  u16x8 r;
  r[0] = f2h(a.x); r[1] = f2h(a.y); r[2] = f2h(a.z); r[3] = f2h(a.w);
  r[4] = f2h(b.x); r[5] = f2h(b.y); r[6] = f2h(b.z); r[7] = f2h(b.w);
  *((u16x8*)o + i) = r;
}

// ---- kernel 2: W [k][n] f32 -> Wt [n][k] f16 ----
__global__ __launch_bounds__(256) void cvt_w(const float* __restrict__ W0,
                                             const float* __restrict__ W1,
                                             const float* __restrict__ W2,
                                             unsigned short* __restrict__ out) {
  __shared__ float t[32][33];
  int z = blockIdx.z;
  const float* W = (z == 0) ? W0 : (z == 1 ? W1 : W2);
  unsigned short* o = out + (size_t)z * 1024 * 1024;
  int c0 = blockIdx.x * 32, r0 = blockIdx.y * 32;
  int tx = threadIdx.x, ty = threadIdx.y;
  for (int i = 0; i < 4; i++)
    t[ty + 8 * i][tx] = W[(size_t)(r0 + ty + 8 * i) * 1024 + c0 + tx];
  __syncthreads();
  for (int i = 0; i < 4; i++)
    o[(size_t)(c0 + ty + 8 * i) * 1024 + r0 + tx] = f2h(t[tx][ty + 8 * i]);
}

// ---- kernel 3: QKV GEMM -> Q,K row-major f16; V transposed [b][d][s] f16 ----
__global__ __launch_bounds__(256) void qkv_gemm(const unsigned short* __restrict__ xb,
                                                const unsigned short* __restrict__ wt,
                                                const float* __restrict__ b0,
                                                const float* __restrict__ b1,
                                                const float* __restrict__ b2,
                                                unsigned short* __restrict__ Qp,
                                                unsigned short* __restrict__ Kp,
                                                unsigned short* __restrict__ vtp) {
  __shared__ unsigned short As[128 * 32];
  __shared__ unsigned short Bs[128 * 32];
  int z = blockIdx.z;
  const unsigned short* W = wt + (size_t)z * 1048576;
  const float* bias = (z == 0) ? b0 : (z == 1 ? b1 : b2);
  int m0 = blockIdx.x * 128, n0 = blockIdx.y * 128;
  int tid = threadIdx.x, lane = tid & 63;
  int w = tid >> 6;
  int wr = w >> 1, wc = w & 1;
  int l15 = lane & 15, l4 = lane >> 4;
  f32x4 acc[4][4] = {};
  for (int kt = 0; kt < 32; ++kt) {
    int k0 = kt * 32;
    u16x8 av[2], bv[2];
    int c0 = tid, c1 = 256 + tid;
    int r0_ = c0 >> 2, cc0 = c0 & 3;
    int r1_ = c1 >> 2, cc1 = c1 & 3;
    av[0] = *(const u16x8*)(xb + (size_t)(m0 + r0_) * 1024 + k0 + cc0 * 8);
    bv[0] = *(const u16x8*)(W  + (size_t)(n0 + r0_) * 1024 + k0 + cc0 * 8);
    av[1] = *(const u16x8*)(xb + (size_t)(m0 + r1_) * 1024 + k0 + cc1 * 8);
    bv[1] = *(const u16x8*)(W  + (size_t)(n0 + r1_) * 1024 + k0 + cc1 * 8);
    __syncthreads();
    *(u16x8*)(As + r0_ * 32 + cc0 * 8) = av[0];
    *(u16x8*)(Bs + r0_ * 32 + cc0 * 8) = bv[0];
    *(u16x8*)(As + r1_ * 32 + cc1 * 8) = av[1];
    *(u16x8*)(Bs + r1_ * 32 + cc1 * 8) = bv[1];
    __syncthreads();
    f16x8 af[4], bfr[4];
    for (int m = 0; m < 4; m++)
      af[m] = *(const f16x8*)(As + (wr * 64 + m * 16 + l15) * 32 + l4 * 8);
    for (int n = 0; n < 4; n++)
      bfr[n] = *(const f16x8*)(Bs + (wc * 64 + n * 16 + l15) * 32 + l4 * 8);
    for (int m = 0; m < 4; m++)
      for (int n = 0; n < 4; n++)
        acc[m][n] = __builtin_amdgcn_mfma_f32_16x16x32_f16(af[m], bfr[n], acc[m][n], 0, 0, 0);
  }
  for (int m = 0; m < 4; m++)
    for (int n = 0; n < 4; n++) {
      int col = n0 + wc * 64 + n * 16 + l15;
      float bvv = bias[col];
      for (int r = 0; r < 4; r++) {
        int row = m0 + wr * 64 + m * 16 + l4 * 4 + r;
        unsigned short val = f2h(acc[m][n][r] + bvv);
        if (z == 0)      Qp[(size_t)row * 1024 + col] = val;
        else if (z == 1) Kp[(size_t)row * 1024 + col] = val;
        else             vtp[((size_t)(row >> 11) * 1024 + col) * 2048 + (row & 2047)] = val;
      }
    }
}

// ---- diag A: verify Q,K,Vt vs raw f32 inputs; sentinel 1e6 ----
__global__ void verify_qkv(const float* __restrict__ x,
                           const float* __restrict__ Wq, const float* __restrict__ Wk,
                           const float* __restrict__ Wv,
                           const float* __restrict__ bq, const float* __restrict__ bk,
                           const float* __restrict__ bv,
                           const unsigned short* __restrict__ Qp,
                           const unsigned short* __restrict__ Kp,
                           const unsigned short* __restrict__ vtp,
                           float* __restrict__ fl) {
  __shared__ int bad;
  int t = threadIdx.x;
  if (t == 0) bad = 0;
  __syncthreads();
  int z = t % 3;
  int m = (t * 97) & 8191;
  int n = (t * 193) & 1023;
  const float* W = (z == 0) ? Wq : (z == 1 ? Wk : Wv);
  const float* bias = (z == 0) ? bq : (z == 1 ? bk : bv);
  float acc = 0.f;
  for (int k = 0; k < 1024; k++)
    acc += x[(size_t)m * 1024 + k] * W[(size_t)k * 1024 + n];
  acc += bias[n];
  float got;
  if (z == 0)      got = h2f(Qp[(size_t)m * 1024 + n]);
  else if (z == 1) got = h2f(Kp[(size_t)m * 1024 + n]);
  else             got = h2f(vtp[((size_t)(m >> 11) * 1024 + n) * 2048 + (m & 2047)]);
  if (fabsf(got - acc) > 0.25f) atomicOr(&bad, 1);
  __syncthreads();
  if (t == 0) fl[0] = bad ? 1.0e6f : 0.f;
}

// ---- kernel 4: scores = Q K^T * SCALE, causal mask, triangular-packed f32 ----
__global__ __launch_bounds__(256) void qk_scores(const unsigned short* __restrict__ Q,
                                                 const unsigned short* __restrict__ Kb,
                                                 float* __restrict__ sc) {
  __shared__ unsigned short As[128 * 32];
  __shared__ unsigned short Bs[128 * 32];
  int b = blockIdx.y;
  int i = blockIdx.x;
  int qt = (int)((sqrtf(8.f * i + 1.f) - 1.f) * 0.5f);
  while ((qt + 1) * (qt + 2) / 2 <= i) qt++;
  while (qt * (qt + 1) / 2 > i) qt--;
  int kt = i - qt * (qt + 1) / 2;
  int Wspan = (qt + 1) << 7;
  const unsigned short* A = Q  + ((size_t)b * 2048 + qt * 128) * 1024;
  const unsigned short* B = Kb + ((size_t)b * 2048 + kt * 128) * 1024;
  float* outp = sc + (size_t)b * P_ELEMS + (size_t)16384 * (qt * (qt + 1) / 2);
  int tid = threadIdx.x, lane = tid & 63;
  int w = tid >> 6;
  int wr = w >> 1, wc = w & 1;
  int l15 = lane & 15, l4 = lane >> 4;
  f32x4 acc[4][4] = {};
  for (int ktp = 0; ktp < 32; ++ktp) {
    int k0 = ktp * 32;
    u16x8 av[2], bv[2];
    int c0 = tid, c1 = 256 + tid;
    int r0_ = c0 >> 2, cc0 = c0 & 3;
    int r1_ = c1 >> 2, cc1 = c1 & 3;
    av[0] = *(const u16x8*)(A + (size_t)r0_ * 1024 + k0 + cc0 * 8);
    bv[0] = *(const u16x8*)(B + (size_t)r0_ * 1024 + k0 + cc0 * 8);
    av[1] = *(const u16x8*)(A + (size_t)r1_ * 1024 + k0 + cc1 * 8);
    bv[1] = *(const u16x8*)(B + (size_t)r1_ * 1024 + k0 + cc1 * 8);
    __syncthreads();
    *(u16x8*)(As + r0_ * 32 + cc0 * 8) = av[0];
    *(u16x8*)(Bs + r0_ * 32 + cc0 * 8) = bv[0];
    *(u16x8*)(As + r1_ * 32 + cc1 * 8) = av[1];
    *(u16x8*)(Bs + r1_ * 32 + cc1 * 8) = bv[1];
    __syncthreads();
    f16x8 af[4], bfr[4];
    for (int m = 0; m < 4; m++)
      af[m] = *(const f16x8*)(As + (wr * 64 + m * 16 + l15) * 32 + l4 * 8);
    for (int n = 0; n < 4; n++)
      bfr[n] = *(const f16x8*)(Bs + (wc * 64 + n * 16 + l15) * 32 + l4 * 8);
    for (int m = 0; m < 4; m++)
      for (int n = 0; n < 4; n++)
        acc[m][n] = __builtin_amdgcn_mfma_f32_16x16x32_f16(af[m], bfr[n], acc[m][n], 0, 0, 0);
  }
  for (int m = 0; m < 4; m++)
    for (int n = 0; n < 4; n++) {
      int cl = wc * 64 + n * 16 + l15;
      int kv = kt * 128 + cl;
      for (int r = 0; r < 4; r++) {
        int rl = wr * 64 + m * 16 + l4 * 4 + r;
        int srow = qt * 128 + rl;
        float v = acc[m][n][r] * SCALE;
        if (kv > srow) v = -1e30f;
        outp[(size_t)rl * Wspan + kv] = v;
      }
    }
}

// ---- kernel 5: row softmax (row in registers), write f16 P packed ----
__global__ __launch_bounds__(256) void softmax_row(const float* __restrict__ sc,
                                                   unsigned short* __restrict__ pb) {
  __shared__ float redm[4];
  __shared__ float reds[4];
  int srow = blockIdx.x;
  int b = srow >> 11, sl = srow & 2047;
  int qt = sl >> 7;
  int Wspan = (qt + 1) << 7;
  size_t rb = (size_t)b * P_ELEMS + (size_t)16384 * (qt * (qt + 1) / 2) + (size_t)(sl & 127) * Wspan;
  const float4* src = (const float4*)(sc + rb);
  int nv = Wspan >> 2;
  int t = threadIdx.x, lane = t & 63, w = t >> 6;
  bool h0 = t < nv, h1 = (t + 256) < nv;
  float4 v0 = make_float4(0, 0, 0, 0), v1 = make_float4(0, 0, 0, 0);
  if (h0) v0 = src[t];
  if (h1) v1 = src[t + 256];
  float mx = -1e30f;
  if (h0) mx = fmaxf(fmaxf(v0.x, v0.y), fmaxf(v0.z, v0.w));
  if (h1) mx = fmaxf(mx, fmaxf(fmaxf(v1.x, v1.y), fmaxf(v1.z, v1.w)));
  for (int off = 1; off < 64; off <<= 1) mx = fmaxf(mx, __shfl_xor(mx, off, 64));
  if (lane == 0) redm[w] = mx;
  __syncthreads();
  mx = fmaxf(fmaxf(redm[0], redm[1]), fmaxf(redm[2], redm[3]));
  float s = 0.f;
  float4 e0, e1;
  if (h0) {
    e0.x = __expf(v0.x - mx); e0.y = __expf(v0.y - mx);
    e0.z = __expf(v0.z - mx); e0.w = __expf(v0.w - mx);
    s += e0.x + e0.y + e0.z + e0.w;
  }
  if (h1) {
    e1.x = __expf(v1.x - mx); e1.y = __expf(v1.y - mx);
    e1.z = __expf(v1.z - mx); e1.w = __expf(v1.w - mx);
    s += e1.x + e1.y + e1.z + e1.w;
  }
  for (int off = 1; off < 64; off <<= 1) s += __shfl_xor(s, off, 64);
  if (lane == 0) reds[w] = s;
  __syncthreads();
  s = reds[0] + reds[1] + reds[2] + reds[3];
  float inv = 1.f / s;
  u16x4* dst = (u16x4*)(pb + rb);
  if (h0) {
    u16x4 o;
    o[0] = f2h(e0.x * inv); o[1] = f2h(e0.y * inv);
    o[2] = f2h(e0.z * inv); o[3] = f2h(e0.w * inv);
    dst[t] = o;
  }
  if (h1) {
    u16x4 o;
    o[0] = f2h(e1.x * inv); o[1] = f2h(e1.y * inv);
    o[2] = f2h(e1.z * inv); o[3] = f2h(e1.w * inv);
    dst[t + 256] = o;
  }
}

// ---- kernel 6: O = P Vt ----
__global__ __launch_bounds__(256) void pv_gemm(const unsigned short* __restrict__ pb,
                                               const unsigned short* __restrict__ vtp,
                                               float* __restrict__ outp) {
  __shared__ unsigned short As[128 * 32];
  __shared__ unsigned short Bs[128 * 32];
  int qt = blockIdx.x;
  int n0 = blockIdx.y * 128;
  int b = blockIdx.z;
  int Wspan = (qt + 1) << 7;
  const unsigned short* A = pb + (size_t)b * P_ELEMS + (size_t)16384 * (qt * (qt + 1) / 2);
  const unsigned short* B = vtp + (size_t)b * 1024 * 2048;
  float* O = outp + ((size_t)b * 2048 + qt * 128) * 1024;
  int tid = threadIdx.x, lane = tid & 63;
  int w = tid >> 6;
  int wr = w >> 1, wc = w & 1;
  int l15 = lane & 15, l4 = lane >> 4;
  f32x4 acc[4][4] = {};
  int nk = Wspan >> 5;
  for (int ktp = 0; ktp < nk; ++ktp) {
    int k0 = ktp * 32;
    u16x8 av[2], bv[2];
    int c0 = tid, c1 = 256 + tid;
    int r0_ = c0 >> 2, cc0 = c0 & 3;
    int r1_ = c1 >> 2, cc1 = c1 & 3;
    av[0] = *(const u16x8*)(A + (size_t)r0_ * Wspan + k0 + cc0 * 8);
    bv[0] = *(const u16x8*)(B + (size_t)(n0 + r0_) * 2048 + k0 + cc0 * 8);
    av[1] = *(const u16x8*)(A + (size_t)r1_ * Wspan + k0 + cc1 * 8);
    bv[1] = *(const u16x8*)(B + (size_t)(n0 + r1_) * 2048 + k0 + cc1 * 8);
    __syncthreads();
    *(u16x8*)(As + r0_ * 32 + cc0 * 8) = av[0];
    *(u16x8*)(Bs + r0_ * 32 + cc0 * 8) = bv[0];
    *(u16x8*)(As + r1_ * 32 + cc1 * 8) = av[1];
    *(u16x8*)(Bs + r1_ * 32 + cc1 * 8) = bv[1];
    __syncthreads();
    f16x8 af[4], bfr[4];
    for (int m = 0; m < 4; m++)
      af[m] = *(const f16x8*)(As + (wr * 64 + m * 16 + l15) * 32 + l4 * 8);
    for (int n = 0; n < 4; n++)
      bfr[n] = *(const f16x8*)(Bs + (wc * 64 + n * 16 + l15) * 32 + l4 * 8);
    for (int m = 0; m < 4; m++)
      for (int n = 0; n < 4; n++)
        acc[m][n] = __builtin_amdgcn_mfma_f32_16x16x32_f16(af[m], bfr[n], acc[m][n], 0, 0, 0);
  }
  for (int m = 0; m < 4; m++)
    for (int n = 0; n < 4; n++) {
      int cl = n0 + wc * 64 + n * 16 + l15;
      for (int r = 0; r < 4; r++) {
        int rl = wr * 64 + m * 16 + l4 * 4 + r;
        O[(size_t)rl * 1024 + cl] = acc[m][n][r];
      }
    }
}

__global__ void apply_flags(const float* __restrict__ fl, float* __restrict__ out) {
  if (threadIdx.x == 0) {
    if (fl[0] != 0.f) out[0] = fl[0];
  }
}

extern "C" void kernel_launch(void* const* d_in, const int* in_sizes, int n_in,
                              void* d_out, int out_size, void* d_ws, size_t ws_size,
                              hipStream_t stream) {
  const float* x  = (const float*)d_in[0];
  const float* Wq = (const float*)d_in[1];
  const float* bq = (const float*)d_in[2];
  const float* Wk = (const float*)d_in[3];
  const float* bk = (const float*)d_in[4];
  const float* Wv = (const float*)d_in[5];
  const float* bv = (const float*)d_in[6];
  float* out = (float*)d_out;

  unsigned short* ws  = (unsigned short*)d_ws;
  unsigned short* wt  = ws;                          // 3,145,728 ushorts
  unsigned short* Qp  = ws + 3145728;                // 8,388,608
  unsigned short* Kp  = ws + 11534336;               // 8,388,608
  unsigned short* vtp = ws + 19922944;               // 8,388,608 (V^T [b][d][s])
  float* sc           = (float*)(ws + 28311552);     // 4*P_ELEMS f32 (packed tri)
  unsigned short* pb  = ws + 46137344;               // 4*P_ELEMS f16 (packed tri)
  float* fl           = (float*)(ws + 55050240);     // flags
  unsigned short* xb  = (unsigned short*)d_out;      // x f16 scratch (overwritten by pv)

  cvt_x<<<4096, 256, 0, stream>>>(x, xb, 1048576);
  cvt_w<<<dim3(32, 32, 3), dim3(32, 8), 0, stream>>>(Wq, Wk, Wv, wt);
  qkv_gemm<<<dim3(64, 8, 3), 256, 0, stream>>>(xb, wt, bq, bk, bv, Qp, Kp, vtp);
  verify_qkv<<<1, 256, 0, stream>>>(x, Wq, Wk, Wv, bq, bk, bv, Qp, Kp, vtp, fl);
  qk_scores<<<dim3(136, 4), 256, 0, stream>>>(Qp, Kp, sc);
  softmax_row<<<8192, 256, 0, stream>>>(sc, pb);
  pv_gemm<<<dim3(16, 8, 4), 256, 0, stream>>>(pb, vtp, out);
  apply_flags<<<1, 64, 0, stream>>>(fl, out);
}

// Round 5
// 201.489 us; speedup vs baseline: 2.5513x; 2.5513x over previous
//
#include <hip/hip_runtime.h>
#include <hip/hip_bf16.h>
#include <cstdint>

#define D_MODEL 1024
#define SEQ     2048
#define SCALE   0.125f
#define P_ELEMS 2228224   // per-batch packed triangular elems: 16384*136

typedef __attribute__((ext_vector_type(8))) _Float16 f16x8;
typedef __attribute__((ext_vector_type(8))) unsigned short u16x8;
typedef __attribute__((ext_vector_type(4))) unsigned short u16x4;
typedef __attribute__((ext_vector_type(4))) float f32x4;

__device__ __forceinline__ unsigned short f2h(float f) {
  _Float16 h = (_Float16)f;
  return __builtin_bit_cast(unsigned short, h);
}

__device__ __forceinline__ void gll16(const void* g, void* lds) {
  __builtin_amdgcn_global_load_lds(
      (const __attribute__((address_space(1))) unsigned int*)(uintptr_t)g,
      (__attribute__((address_space(3))) unsigned int*)(unsigned int)(uintptr_t)lds,
      16, 0, 0);
}

// ---- kernel 1: x f32 -> f16 ----
__global__ __launch_bounds__(256) void cvt_x(const float* __restrict__ x,
                                             unsigned short* __restrict__ o, int n8) {
  int i = blockIdx.x * 256 + threadIdx.x;
  if (i >= n8) return;
  const float4* p = (const float4*)x + (size_t)i * 2;
  float4 a = p[0], b = p[1];
  u16x8 r;
  r[0] = f2h(a.x); r[1] = f2h(a.y); r[2] = f2h(a.z); r[3] = f2h(a.w);
  r[4] = f2h(b.x); r[5] = f2h(b.y); r[6] = f2h(b.z); r[7] = f2h(b.w);
  *((u16x8*)o + i) = r;
}

// ---- kernel 2: W [k][n] f32 -> Wt [n][k] f16 ----
__global__ __launch_bounds__(256) void cvt_w(const float* __restrict__ W0,
                                             const float* __restrict__ W1,
                                             const float* __restrict__ W2,
                                             unsigned short* __restrict__ out) {
  __shared__ float t[32][33];
  int z = blockIdx.z;
  const float* W = (z == 0) ? W0 : (z == 1 ? W1 : W2);
  unsigned short* o = out + (size_t)z * 1024 * 1024;
  int c0 = blockIdx.x * 32, r0 = blockIdx.y * 32;
  int tx = threadIdx.x, ty = threadIdx.y;
  for (int i = 0; i < 4; i++)
    t[ty + 8 * i][tx] = W[(size_t)(r0 + ty + 8 * i) * 1024 + c0 + tx];
  __syncthreads();
  for (int i = 0; i < 4; i++)
    o[(size_t)(c0 + ty + 8 * i) * 1024 + r0 + tx] = f2h(t[tx][ty + 8 * i]);
}

// ---- kernel 3: QKV GEMM -> Q,K row-major f16; V transposed [b][d][s] f16 ----
__global__ __launch_bounds__(256) void qkv_gemm(const unsigned short* __restrict__ xb,
                                                const unsigned short* __restrict__ wt,
                                                const float* __restrict__ b0,
                                                const float* __restrict__ b1,
                                                const float* __restrict__ b2,
                                                unsigned short* __restrict__ Qp,
                                                unsigned short* __restrict__ Kp,
                                                unsigned short* __restrict__ vtp) {
  __shared__ unsigned short As[128 * 32];
  __shared__ unsigned short Bs[128 * 32];
  int z = blockIdx.z;
  const unsigned short* W = wt + (size_t)z * 1048576;
  const float* bias = (z == 0) ? b0 : (z == 1 ? b1 : b2);
  int m0 = blockIdx.x * 128, n0 = blockIdx.y * 128;
  int tid = threadIdx.x, lane = tid & 63;
  int w = tid >> 6;
  int wr = w >> 1, wc = w & 1;
  int l15 = lane & 15, l4 = lane >> 4;
  f32x4 acc[4][4] = {};
  for (int kt = 0; kt < 32; ++kt) {
    int k0 = kt * 32;
    for (int i = 0; i < 2; i++) {
      int c = (i * 4 + w) * 64 + lane;
      int row = c >> 2, cc = c & 3;
      gll16(xb + (size_t)(m0 + row) * 1024 + k0 + cc * 8, (char*)As + (i * 4 + w) * 1024);
      gll16(W  + (size_t)(n0 + row) * 1024 + k0 + cc * 8, (char*)Bs + (i * 4 + w) * 1024);
    }
    __syncthreads();
    f16x8 af[4], bfr[4];
    for (int m = 0; m < 4; m++)
      af[m] = *(const f16x8*)(As + (wr * 64 + m * 16 + l15) * 32 + l4 * 8);
    for (int n = 0; n < 4; n++)
      bfr[n] = *(const f16x8*)(Bs + (wc * 64 + n * 16 + l15) * 32 + l4 * 8);
    for (int m = 0; m < 4; m++)
      for (int n = 0; n < 4; n++)
        acc[m][n] = __builtin_amdgcn_mfma_f32_16x16x32_f16(af[m], bfr[n], acc[m][n], 0, 0, 0);
    __syncthreads();
  }
  for (int m = 0; m < 4; m++)
    for (int n = 0; n < 4; n++) {
      int col = n0 + wc * 64 + n * 16 + l15;
      float bvv = bias[col];
      for (int r = 0; r < 4; r++) {
        int row = m0 + wr * 64 + m * 16 + l4 * 4 + r;
        unsigned short val = f2h(acc[m][n][r] + bvv);
        if (z == 0)      Qp[(size_t)row * 1024 + col] = val;
        else if (z == 1) Kp[(size_t)row * 1024 + col] = val;
        else             vtp[((size_t)(row >> 11) * 1024 + col) * 2048 + (row & 2047)] = val;
      }
    }
}

// ---- kernel 4: scores = Q K^T * SCALE, causal mask, triangular-packed f32 ----
__global__ __launch_bounds__(256) void qk_scores(const unsigned short* __restrict__ Q,
                                                 const unsigned short* __restrict__ Kb,
                                                 float* __restrict__ sc) {
  __shared__ unsigned short As[128 * 32];
  __shared__ unsigned short Bs[128 * 32];
  int b = blockIdx.y;
  int i = blockIdx.x;
  int qt = (int)((sqrtf(8.f * i + 1.f) - 1.f) * 0.5f);
  while ((qt + 1) * (qt + 2) / 2 <= i) qt++;
  while (qt * (qt + 1) / 2 > i) qt--;
  int kt = i - qt * (qt + 1) / 2;
  int Wspan = (qt + 1) << 7;
  const unsigned short* A = Q  + ((size_t)b * 2048 + qt * 128) * 1024;
  const unsigned short* B = Kb + ((size_t)b * 2048 + kt * 128) * 1024;
  float* outp = sc + (size_t)b * P_ELEMS + (size_t)16384 * (qt * (qt + 1) / 2);
  int tid = threadIdx.x, lane = tid & 63;
  int w = tid >> 6;
  int wr = w >> 1, wc = w & 1;
  int l15 = lane & 15, l4 = lane >> 4;
  f32x4 acc[4][4] = {};
  for (int ktp = 0; ktp < 32; ++ktp) {
    int k0 = ktp * 32;
    for (int i2 = 0; i2 < 2; i2++) {
      int c = (i2 * 4 + w) * 64 + lane;
      int row = c >> 2, cc = c & 3;
      gll16(A + (size_t)row * 1024 + k0 + cc * 8, (char*)As + (i2 * 4 + w) * 1024);
      gll16(B + (size_t)row * 1024 + k0 + cc * 8, (char*)Bs + (i2 * 4 + w) * 1024);
    }
    __syncthreads();
    f16x8 af[4], bfr[4];
    for (int m = 0; m < 4; m++)
      af[m] = *(const f16x8*)(As + (wr * 64 + m * 16 + l15) * 32 + l4 * 8);
    for (int n = 0; n < 4; n++)
      bfr[n] = *(const f16x8*)(Bs + (wc * 64 + n * 16 + l15) * 32 + l4 * 8);
    for (int m = 0; m < 4; m++)
      for (int n = 0; n < 4; n++)
        acc[m][n] = __builtin_amdgcn_mfma_f32_16x16x32_f16(af[m], bfr[n], acc[m][n], 0, 0, 0);
    __syncthreads();
  }
  for (int m = 0; m < 4; m++)
    for (int n = 0; n < 4; n++) {
      int cl = wc * 64 + n * 16 + l15;
      int kv = kt * 128 + cl;
      for (int r = 0; r < 4; r++) {
        int rl = wr * 64 + m * 16 + l4 * 4 + r;
        int srow = qt * 128 + rl;
        float v = acc[m][n][r] * SCALE;
        if (kv > srow) v = -1e30f;
        outp[(size_t)rl * Wspan + kv] = v;
      }
    }
}

// ---- kernel 5: row softmax (row in registers), write f16 P packed ----
__global__ __launch_bounds__(256) void softmax_row(const float* __restrict__ sc,
                                                   unsigned short* __restrict__ pb) {
  __shared__ float redm[4];
  __shared__ float reds[4];
  int srow = blockIdx.x;
  int b = srow >> 11, sl = srow & 2047;
  int qt = sl >> 7;
  int Wspan = (qt + 1) << 7;
  size_t rb = (size_t)b * P_ELEMS + (size_t)16384 * (qt * (qt + 1) / 2) + (size_t)(sl & 127) * Wspan;
  const float4* src = (const float4*)(sc + rb);
  int nv = Wspan >> 2;
  int t = threadIdx.x, lane = t & 63, w = t >> 6;
  bool h0 = t < nv, h1 = (t + 256) < nv;
  float4 v0 = make_float4(0, 0, 0, 0), v1 = make_float4(0, 0, 0, 0);
  if (h0) v0 = src[t];
  if (h1) v1 = src[t + 256];
  float mx = -1e30f;
  if (h0) mx = fmaxf(fmaxf(v0.x, v0.y), fmaxf(v0.z, v0.w));
  if (h1) mx = fmaxf(mx, fmaxf(fmaxf(v1.x, v1.y), fmaxf(v1.z, v1.w)));
  for (int off = 1; off < 64; off <<= 1) mx = fmaxf(mx, __shfl_xor(mx, off, 64));
  if (lane == 0) redm[w] = mx;
  __syncthreads();
  mx = fmaxf(fmaxf(redm[0], redm[1]), fmaxf(redm[2], redm[3]));
  float s = 0.f;
  float4 e0, e1;
  if (h0) {
    e0.x = __expf(v0.x - mx); e0.y = __expf(v0.y - mx);
    e0.z = __expf(v0.z - mx); e0.w = __expf(v0.w - mx);
    s += e0.x + e0.y + e0.z + e0.w;
  }
  if (h1) {
    e1.x = __expf(v1.x - mx); e1.y = __expf(v1.y - mx);
    e1.z = __expf(v1.z - mx); e1.w = __expf(v1.w - mx);
    s += e1.x + e1.y + e1.z + e1.w;
  }
  for (int off = 1; off < 64; off <<= 1) s += __shfl_xor(s, off, 64);
  if (lane == 0) reds[w] = s;
  __syncthreads();
  s = reds[0] + reds[1] + reds[2] + reds[3];
  float inv = 1.f / s;
  u16x4* dst = (u16x4*)(pb + rb);
  if (h0) {
    u16x4 o;
    o[0] = f2h(e0.x * inv); o[1] = f2h(e0.y * inv);
    o[2] = f2h(e0.z * inv); o[3] = f2h(e0.w * inv);
    dst[t] = o;
  }
  if (h1) {
    u16x4 o;
    o[0] = f2h(e1.x * inv); o[1] = f2h(e1.y * inv);
    o[2] = f2h(e1.z * inv); o[3] = f2h(e1.w * inv);
    dst[t + 256] = o;
  }
}

// ---- kernel 6: O = P Vt ----
__global__ __launch_bounds__(256) void pv_gemm(const unsigned short* __restrict__ pb,
                                               const unsigned short* __restrict__ vtp,
                                               float* __restrict__ outp) {
  __shared__ unsigned short As[128 * 32];
  __shared__ unsigned short Bs[128 * 32];
  int qt = blockIdx.x;
  int n0 = blockIdx.y * 128;
  int b = blockIdx.z;
  int Wspan = (qt + 1) << 7;
  const unsigned short* A = pb + (size_t)b * P_ELEMS + (size_t)16384 * (qt * (qt + 1) / 2);
  const unsigned short* B = vtp + (size_t)b * 1024 * 2048;
  float* O = outp + ((size_t)b * 2048 + qt * 128) * 1024;
  int tid = threadIdx.x, lane = tid & 63;
  int w = tid >> 6;
  int wr = w >> 1, wc = w & 1;
  int l15 = lane & 15, l4 = lane >> 4;
  f32x4 acc[4][4] = {};
  int nk = Wspan >> 5;
  for (int ktp = 0; ktp < nk; ++ktp) {
    int k0 = ktp * 32;
    for (int i2 = 0; i2 < 2; i2++) {
      int c = (i2 * 4 + w) * 64 + lane;
      int row = c >> 2, cc = c & 3;
      gll16(A + (size_t)row * Wspan + k0 + cc * 8, (char*)As + (i2 * 4 + w) * 1024);
      gll16(B + (size_t)(n0 + row) * 2048 + k0 + cc * 8, (char*)Bs + (i2 * 4 + w) * 1024);
    }
    __syncthreads();
    f16x8 af[4], bfr[4];
    for (int m = 0; m < 4; m++)
      af[m] = *(const f16x8*)(As + (wr * 64 + m * 16 + l15) * 32 + l4 * 8);
    for (int n = 0; n < 4; n++)
      bfr[n] = *(const f16x8*)(Bs + (wc * 64 + n * 16 + l15) * 32 + l4 * 8);
    for (int m = 0; m < 4; m++)
      for (int n = 0; n < 4; n++)
        acc[m][n] = __builtin_amdgcn_mfma_f32_16x16x32_f16(af[m], bfr[n], acc[m][n], 0, 0, 0);
    __syncthreads();
  }
  for (int m = 0; m < 4; m++)
    for (int n = 0; n < 4; n++) {
      int cl = n0 + wc * 64 + n * 16 + l15;
      for (int r = 0; r < 4; r++) {
        int rl = wr * 64 + m * 16 + l4 * 4 + r;
        O[(size_t)rl * 1024 + cl] = acc[m][n][r];
      }
    }
}

extern "C" void kernel_launch(void* const* d_in, const int* in_sizes, int n_in,
                              void* d_out, int out_size, void* d_ws, size_t ws_size,
                              hipStream_t stream) {
  const float* x  = (const float*)d_in[0];
  const float* Wq = (const float*)d_in[1];
  const float* bq = (const float*)d_in[2];
  const float* Wk = (const float*)d_in[3];
  const float* bk = (const float*)d_in[4];
  const float* Wv = (const float*)d_in[5];
  const float* bv = (const float*)d_in[6];
  float* out = (float*)d_out;

  unsigned short* ws  = (unsigned short*)d_ws;
  unsigned short* wt  = ws;                          // 3,145,728 ushorts
  unsigned short* Qp  = ws + 3145728;                // 8,388,608
  unsigned short* Kp  = ws + 11534336;               // 8,388,608
  unsigned short* vtp = ws + 19922944;               // 8,388,608 (V^T [b][d][s])
  float* sc           = (float*)(ws + 28311552);     // 4*P_ELEMS f32 (packed tri)
  unsigned short* pb  = ws + 46137344;               // 4*P_ELEMS f16 (packed tri)
  unsigned short* xb  = (unsigned short*)d_out;      // x f16 scratch (overwritten by pv)

  cvt_x<<<4096, 256, 0, stream>>>(x, xb, 1048576);
  cvt_w<<<dim3(32, 32, 3), dim3(32, 8), 0, stream>>>(Wq, Wk, Wv, wt);
  qkv_gemm<<<dim3(64, 8, 3), 256, 0, stream>>>(xb, wt, bq, bk, bv, Qp, Kp, vtp);
  qk_scores<<<dim3(136, 4), 256, 0, stream>>>(Qp, Kp, sc);
  softmax_row<<<8192, 256, 0, stream>>>(sc, pb);
  pv_gemm<<<dim3(16, 8, 4), 256, 0, stream>>>(pb, vtp, out);
}

// Round 6
// 178.088 us; speedup vs baseline: 2.8865x; 1.1314x over previous
//
#include <hip/hip_runtime.h>
#include <hip/hip_bf16.h>
#include <cstdint>

#define D_MODEL 1024
#define SEQ     2048
#define SCALE   0.125f
#define P_ELEMS 2228224   // per-batch packed triangular elems: 16384*136

typedef __attribute__((ext_vector_type(8))) _Float16 f16x8;
typedef __attribute__((ext_vector_type(8))) unsigned short u16x8;
typedef __attribute__((ext_vector_type(4))) unsigned short u16x4;
typedef __attribute__((ext_vector_type(4))) float f32x4;

__device__ __forceinline__ unsigned short f2h(float f) {
  _Float16 h = (_Float16)f;
  return __builtin_bit_cast(unsigned short, h);
}

__device__ __forceinline__ void gll16(const void* g, void* lds_p) {
  __builtin_amdgcn_global_load_lds(
      (const __attribute__((address_space(1))) unsigned int*)(uintptr_t)g,
      (__attribute__((address_space(3))) unsigned int*)(unsigned int)(uintptr_t)lds_p,
      16, 0, 0);
}

#define WAITV8 asm volatile("s_waitcnt vmcnt(8)" ::: "memory")
#define WAITV0 asm volatile("s_waitcnt vmcnt(0)" ::: "memory")
#define WAITL0 asm volatile("s_waitcnt lgkmcnt(0)" ::: "memory")
#define SCHEDB __builtin_amdgcn_sched_barrier(0)
#define BAR    __builtin_amdgcn_s_barrier()

// Stage one K-tile: A[128][64] + B[128][64] f16, source-pre-swizzled so that
// LDS[row][slot] = G[row][slot ^ (row&7)]  (slot = 16B unit). gll dest linear.
__device__ __forceinline__ void stage_tile(const unsigned short* gA, const unsigned short* gB,
                                           int k0, unsigned short* buf, int w, int lane) {
  int rl = lane >> 3;                      // row-within-8  == row&7
  int sg = ((lane & 7) ^ rl) << 3;         // swizzled source slot, in elements
#pragma unroll
  for (int j = 0; j < 4; j++) {
    int c = w * 4 + j;                     // chunk 0..15 (8 rows each)
    int row = c * 8 + rl;
    gll16(gA + (size_t)row * 1024 + k0 + sg, buf + c * 512);
    gll16(gB + (size_t)row * 1024 + k0 + sg, buf + 8192 + c * 512);
  }
}

// Read all MFMA fragments of the current K-tile (swizzled addressing).
__device__ __forceinline__ void load_frags(const unsigned short* buf, int wr, int wc,
                                           int l15, int l4, f16x8 af[4][2], f16x8 bf[4][2]) {
  const unsigned short* bA = buf;
  const unsigned short* bB = buf + 8192;
#pragma unroll
  for (int m = 0; m < 4; m++) {
    int row = wr * 64 + m * 16 + l15, rs = row & 7;
    af[m][0] = *(const f16x8*)(bA + row * 64 + ((l4 ^ rs) << 3));
    af[m][1] = *(const f16x8*)(bA + row * 64 + (((4 + l4) ^ rs) << 3));
  }
#pragma unroll
  for (int n = 0; n < 4; n++) {
    int row = wc * 64 + n * 16 + l15, rs = row & 7;
    bf[n][0] = *(const f16x8*)(bB + row * 64 + ((l4 ^ rs) << 3));
    bf[n][1] = *(const f16x8*)(bB + row * 64 + (((4 + l4) ^ rs) << 3));
  }
}

__device__ __forceinline__ void mfma_tile(f16x8 af[4][2], f16x8 bf[4][2], f32x4 acc[4][4]) {
#pragma unroll
  for (int m = 0; m < 4; m++)
#pragma unroll
    for (int n = 0; n < 4; n++) {
      acc[m][n] = __builtin_amdgcn_mfma_f32_16x16x32_f16(af[m][0], bf[n][0], acc[m][n], 0, 0, 0);
      acc[m][n] = __builtin_amdgcn_mfma_f32_16x16x32_f16(af[m][1], bf[n][1], acc[m][n], 0, 0, 0);
    }
}

// Deep-pipelined K-loop: tile t in lds[t&1]; stage t+2 into the just-freed buffer;
// counted vmcnt(8) keeps t+2's loads in flight across barriers. nt must be even.
__device__ __forceinline__ void gemm_core(const unsigned short* gA, const unsigned short* gB,
                                          unsigned short* lds0, unsigned short* lds1, int nt,
                                          int w, int lane, int wr, int wc, int l15, int l4,
                                          f32x4 acc[4][4]) {
  stage_tile(gA, gB, 0, lds0, w, lane);
  stage_tile(gA, gB, 64, lds1, w, lane);
  WAITV8; SCHEDB; BAR;
  f16x8 af[4][2], bf[4][2];
  for (int t = 0; t < nt; t += 2) {
    // even sub-iter: buffer lds0, tile t
    load_frags(lds0, wr, wc, l15, l4, af, bf);
    WAITL0; SCHEDB; BAR;                       // all waves done reading lds0
    if (t + 2 < nt) stage_tile(gA, gB, (t + 2) * 64, lds0, w, lane);
    __builtin_amdgcn_s_setprio(1);
    mfma_tile(af, bf, acc);
    __builtin_amdgcn_s_setprio(0);
    if (t + 2 < nt) { WAITV8; } else { WAITV0; }   // tile t+1 landed
    SCHEDB; BAR;
    // odd sub-iter: buffer lds1, tile t+1
    load_frags(lds1, wr, wc, l15, l4, af, bf);
    WAITL0; SCHEDB; BAR;
    if (t + 3 < nt) stage_tile(gA, gB, (t + 3) * 64, lds1, w, lane);
    __builtin_amdgcn_s_setprio(1);
    mfma_tile(af, bf, acc);
    __builtin_amdgcn_s_setprio(0);
    if (t + 3 < nt) { WAITV8; } else { WAITV0; }
    SCHEDB; BAR;
  }
}

// ---- kernel 1: x f32 -> f16 ----
__global__ __launch_bounds__(256) void cvt_x(const float* __restrict__ x,
                                             unsigned short* __restrict__ o, int n8) {
  int i = blockIdx.x * 256 + threadIdx.x;
  if (i >= n8) return;
  const float4* p = (const float4*)x + (size_t)i * 2;
  float4 a = p[0], b = p[1];
  u16x8 r;
  r[0] = f2h(a.x); r[1] = f2h(a.y); r[2] = f2h(a.z); r[3] = f2h(a.w);
  r[4] = f2h(b.x); r[5] = f2h(b.y); r[6] = f2h(b.z); r[7] = f2h(b.w);
  *((u16x8*)o + i) = r;
}

// ---- kernel 2: W [k][n] f32 -> Wt [n][k] f16 ----
__global__ __launch_bounds__(256) void cvt_w(const float* __restrict__ W0,
                                             const float* __restrict__ W1,
                                             const float* __restrict__ W2,
                                             unsigned short* __restrict__ out) {
  __shared__ float t[32][33];
  int z = blockIdx.z;
  const float* W = (z == 0) ? W0 : (z == 1 ? W1 : W2);
  unsigned short* o = out + (size_t)z * 1024 * 1024;
  int c0 = blockIdx.x * 32, r0 = blockIdx.y * 32;
  int tx = threadIdx.x, ty = threadIdx.y;
  for (int i = 0; i < 4; i++)
    t[ty + 8 * i][tx] = W[(size_t)(r0 + ty + 8 * i) * 1024 + c0 + tx];
  __syncthreads();
  for (int i = 0; i < 4; i++)
    o[(size_t)(c0 + ty + 8 * i) * 1024 + r0 + tx] = f2h(t[tx][ty + 8 * i]);
}

// ---- kernel 3: fused QKV GEMM (N=3072), deep pipeline; V written transposed+coalesced ----
__global__ __launch_bounds__(256) void qkv_gemm(const unsigned short* __restrict__ xb,
                                                const unsigned short* __restrict__ wt,
                                                const float* __restrict__ b0,
                                                const float* __restrict__ b1,
                                                const float* __restrict__ b2,
                                                unsigned short* __restrict__ Qp,
                                                unsigned short* __restrict__ Kp,
                                                unsigned short* __restrict__ vtp) {
  __shared__ unsigned short lds[2][16384];   // [buf][A 8192 | B 8192]
  int m0 = blockIdx.x * 128;
  int n0 = blockIdx.y * 128;
  int z = n0 >> 10, nz = n0 & 1023;
  const unsigned short* gA = xb + (size_t)m0 * 1024;
  const unsigned short* gB = wt + (size_t)z * 1048576 + (size_t)nz * 1024;
  const float* bias = (z == 0) ? b0 : (z == 1 ? b1 : b2);
  int tid = threadIdx.x, lane = tid & 63, w = tid >> 6;
  int wr = w >> 1, wc = w & 1, l15 = lane & 15, l4 = lane >> 4;
  f32x4 acc[4][4] = {};
  gemm_core(gA, gB, &lds[0][0], &lds[1][0], 16, w, lane, wr, wc, l15, l4, acc);

  if (z < 2) {
    unsigned short* O = (z == 0) ? Qp : Kp;
#pragma unroll
    for (int m = 0; m < 4; m++)
#pragma unroll
      for (int n = 0; n < 4; n++) {
        int cl = wc * 64 + n * 16 + l15;
        float bv = bias[nz + cl];
#pragma unroll
        for (int r = 0; r < 4; r++) {
          int row = m0 + wr * 64 + m * 16 + l4 * 4 + r;
          O[(size_t)row * 1024 + nz + cl] = f2h(acc[m][n][r] + bv);
        }
      }
  } else {
    // V: transpose 128x128 tile in LDS, then coalesced store to vtp[b][d][s]
    unsigned short* T = &lds[0][0];          // 128 x 136 f16 = 34 KB (fits in 64 KB)
#pragma unroll
    for (int m = 0; m < 4; m++)
#pragma unroll
      for (int n = 0; n < 4; n++) {
        int cl = wc * 64 + n * 16 + l15;     // d-local
        float bv = bias[nz + cl];
#pragma unroll
        for (int r = 0; r < 4; r++) {
          int rl = wr * 64 + m * 16 + l4 * 4 + r;   // s-local
          T[cl * 136 + rl] = f2h(acc[m][n][r] + bv);
        }
      }
    __syncthreads();
    int bidx = m0 >> 11, s0 = m0 & 2047;
#pragma unroll
    for (int i = 0; i < 8; i++) {
      int d = w * 32 + i * 4 + (lane >> 4);
      int ch = lane & 15;
      u16x8 v = *(const u16x8*)(T + d * 136 + ch * 8);
      *(u16x8*)(vtp + ((size_t)bidx * 1024 + nz + d) * 2048 + s0 + ch * 8) = v;
    }
  }
}

// ---- kernel 4: scores = Q K^T * SCALE, causal mask, triangular-packed f32 ----
__global__ __launch_bounds__(256) void qk_scores(const unsigned short* __restrict__ Q,
                                                 const unsigned short* __restrict__ Kb,
                                                 float* __restrict__ sc) {
  __shared__ unsigned short lds[2][16384];
  int b = blockIdx.y;
  int i = blockIdx.x;
  int qt = (int)((sqrtf(8.f * i + 1.f) - 1.f) * 0.5f);
  while ((qt + 1) * (qt + 2) / 2 <= i) qt++;
  while (qt * (qt + 1) / 2 > i) qt--;
  int kt = i - qt * (qt + 1) / 2;
  int Wspan = (qt + 1) << 7;
  const unsigned short* gA = Q  + ((size_t)b * 2048 + qt * 128) * 1024;
  const unsigned short* gB = Kb + ((size_t)b * 2048 + kt * 128) * 1024;
  float* outp = sc + (size_t)b * P_ELEMS + (size_t)16384 * (qt * (qt + 1) / 2);
  int tid = threadIdx.x, lane = tid & 63, w = tid >> 6;
  int wr = w >> 1, wc = w & 1, l15 = lane & 15, l4 = lane >> 4;
  f32x4 acc[4][4] = {};
  gemm_core(gA, gB, &lds[0][0], &lds[1][0], 16, w, lane, wr, wc, l15, l4, acc);
#pragma unroll
  for (int m = 0; m < 4; m++)
#pragma unroll
    for (int n = 0; n < 4; n++) {
      int cl = wc * 64 + n * 16 + l15;
      int kv = kt * 128 + cl;
#pragma unroll
      for (int r = 0; r < 4; r++) {
        int rl = wr * 64 + m * 16 + l4 * 4 + r;
        int srow = qt * 128 + rl;
        float v = acc[m][n][r] * SCALE;
        if (kv > srow) v = -1e30f;
        outp[(size_t)rl * Wspan + kv] = v;
      }
    }
}

// ---- kernel 5: row softmax (row in registers), write f16 P packed ----
__global__ __launch_bounds__(256) void softmax_row(const float* __restrict__ sc,
                                                   unsigned short* __restrict__ pb) {
  __shared__ float redm[4];
  __shared__ float reds[4];
  int srow = blockIdx.x;
  int b = srow >> 11, sl = srow & 2047;
  int qt = sl >> 7;
  int Wspan = (qt + 1) << 7;
  size_t rb = (size_t)b * P_ELEMS + (size_t)16384 * (qt * (qt + 1) / 2) + (size_t)(sl & 127) * Wspan;
  const float4* src = (const float4*)(sc + rb);
  int nv = Wspan >> 2;
  int t = threadIdx.x, lane = t & 63, w = t >> 6;
  bool h0 = t < nv, h1 = (t + 256) < nv;
  float4 v0 = make_float4(0, 0, 0, 0), v1 = make_float4(0, 0, 0, 0);
  if (h0) v0 = src[t];
  if (h1) v1 = src[t + 256];
  float mx = -1e30f;
  if (h0) mx = fmaxf(fmaxf(v0.x, v0.y), fmaxf(v0.z, v0.w));
  if (h1) mx = fmaxf(mx, fmaxf(fmaxf(v1.x, v1.y), fmaxf(v1.z, v1.w)));
  for (int off = 1; off < 64; off <<= 1) mx = fmaxf(mx, __shfl_xor(mx, off, 64));
  if (lane == 0) redm[w] = mx;
  __syncthreads();
  mx = fmaxf(fmaxf(redm[0], redm[1]), fmaxf(redm[2], redm[3]));
  float s = 0.f;
  float4 e0, e1;
  if (h0) {
    e0.x = __expf(v0.x - mx); e0.y = __expf(v0.y - mx);
    e0.z = __expf(v0.z - mx); e0.w = __expf(v0.w - mx);
    s += e0.x + e0.y + e0.z + e0.w;
  }
  if (h1) {
    e1.x = __expf(v1.x - mx); e1.y = __expf(v1.y - mx);
    e1.z = __expf(v1.z - mx); e1.w = __expf(v1.w - mx);
    s += e1.x + e1.y + e1.z + e1.w;
  }
  for (int off = 1; off < 64; off <<= 1) s += __shfl_xor(s, off, 64);
  if (lane == 0) reds[w] = s;
  __syncthreads();
  s = reds[0] + reds[1] + reds[2] + reds[3];
  float inv = 1.f / s;
  u16x4* dst = (u16x4*)(pb + rb);
  if (h0) {
    u16x4 o;
    o[0] = f2h(e0.x * inv); o[1] = f2h(e0.y * inv);
    o[2] = f2h(e0.z * inv); o[3] = f2h(e0.w * inv);
    dst[t] = o;
  }
  if (h1) {
    u16x4 o;
    o[0] = f2h(e1.x * inv); o[1] = f2h(e1.y * inv);
    o[2] = f2h(e1.z * inv); o[3] = f2h(e1.w * inv);
    dst[t + 256] = o;
  }
}

// ---- kernel 6: O = P Vt (unchanged r5 structure) ----
__global__ __launch_bounds__(256) void pv_gemm(const unsigned short* __restrict__ pb,
                                               const unsigned short* __restrict__ vtp,
                                               float* __restrict__ outp) {
  __shared__ unsigned short As[128 * 32];
  __shared__ unsigned short Bs[128 * 32];
  int qt = blockIdx.x;
  int n0 = blockIdx.y * 128;
  int b = blockIdx.z;
  int Wspan = (qt + 1) << 7;
  const unsigned short* A = pb + (size_t)b * P_ELEMS + (size_t)16384 * (qt * (qt + 1) / 2);
  const unsigned short* B = vtp + (size_t)b * 1024 * 2048;
  float* O = outp + ((size_t)b * 2048 + qt * 128) * 1024;
  int tid = threadIdx.x, lane = tid & 63;
  int w = tid >> 6;
  int wr = w >> 1, wc = w & 1;
  int l15 = lane & 15, l4 = lane >> 4;
  f32x4 acc[4][4] = {};
  int nk = Wspan >> 5;
  for (int ktp = 0; ktp < nk; ++ktp) {
    int k0 = ktp * 32;
    for (int i2 = 0; i2 < 2; i2++) {
      int c = (i2 * 4 + w) * 64 + lane;
      int row = c >> 2, cc = c & 3;
      gll16(A + (size_t)row * Wspan + k0 + cc * 8, (char*)As + (i2 * 4 + w) * 1024);
      gll16(B + (size_t)(n0 + row) * 2048 + k0 + cc * 8, (char*)Bs + (i2 * 4 + w) * 1024);
    }
    __syncthreads();
    f16x8 af[4], bfr[4];
    for (int m = 0; m < 4; m++)
      af[m] = *(const f16x8*)(As + (wr * 64 + m * 16 + l15) * 32 + l4 * 8);
    for (int n = 0; n < 4; n++)
      bfr[n] = *(const f16x8*)(Bs + (wc * 64 + n * 16 + l15) * 32 + l4 * 8);
    for (int m = 0; m < 4; m++)
      for (int n = 0; n < 4; n++)
        acc[m][n] = __builtin_amdgcn_mfma_f32_16x16x32_f16(af[m], bfr[n], acc[m][n], 0, 0, 0);
    __syncthreads();
  }
  for (int m = 0; m < 4; m++)
    for (int n = 0; n < 4; n++) {
      int cl = n0 + wc * 64 + n * 16 + l15;
      for (int r = 0; r < 4; r++) {
        int rl = wr * 64 + m * 16 + l4 * 4 + r;
        O[(size_t)rl * 1024 + cl] = acc[m][n][r];
      }
    }
}

extern "C" void kernel_launch(void* const* d_in, const int* in_sizes, int n_in,
                              void* d_out, int out_size, void* d_ws, size_t ws_size,
                              hipStream_t stream) {
  const float* x  = (const float*)d_in[0];
  const float* Wq = (const float*)d_in[1];
  const float* bq = (const float*)d_in[2];
  const float* Wk = (const float*)d_in[3];
  const float* bk = (const float*)d_in[4];
  const float* Wv = (const float*)d_in[5];
  const float* bv = (const float*)d_in[6];
  float* out = (float*)d_out;

  unsigned short* ws  = (unsigned short*)d_ws;
  unsigned short* wt  = ws;                          // 3,145,728 ushorts
  unsigned short* Qp  = ws + 3145728;                // 8,388,608
  unsigned short* Kp  = ws + 11534336;               // 8,388,608
  unsigned short* vtp = ws + 19922944;               // 8,388,608 (V^T [b][d][s])
  float* sc           = (float*)(ws + 28311552);     // 4*P_ELEMS f32 (packed tri)
  unsigned short* pb  = ws + 46137344;               // 4*P_ELEMS f16 (packed tri)
  unsigned short* xb  = (unsigned short*)d_out;      // x f16 scratch (overwritten by pv)

  cvt_x<<<4096, 256, 0, stream>>>(x, xb, 1048576);
  cvt_w<<<dim3(32, 32, 3), dim3(32, 8), 0, stream>>>(Wq, Wk, Wv, wt);
  qkv_gemm<<<dim3(64, 24), 256, 0, stream>>>(xb, wt, bq, bk, bv, Qp, Kp, vtp);
  qk_scores<<<dim3(136, 4), 256, 0, stream>>>(Qp, Kp, sc);
  softmax_row<<<8192, 256, 0, stream>>>(sc, pb);
  pv_gemm<<<dim3(16, 8, 4), 256, 0, stream>>>(pb, vtp, out);
}

// Round 7
// 156.723 us; speedup vs baseline: 3.2800x; 1.1363x over previous
//
#include <hip/hip_runtime.h>
#include <hip/hip_bf16.h>
#include <cstdint>

#define D_MODEL 1024
#define SEQ     2048
#define SCALE   0.125f
#define P_ELEMS 2228224   // per-batch packed triangular elems: 16384*136

typedef __attribute__((ext_vector_type(8))) _Float16 f16x8;
typedef __attribute__((ext_vector_type(8))) unsigned short u16x8;
typedef __attribute__((ext_vector_type(4))) unsigned short u16x4;
typedef __attribute__((ext_vector_type(4))) float f32x4;

__device__ __forceinline__ unsigned short f2h(float f) {
  _Float16 h = (_Float16)f;
  return __builtin_bit_cast(unsigned short, h);
}

__device__ __forceinline__ void gll16(const void* g, void* lds_p) {
  __builtin_amdgcn_global_load_lds(
      (const __attribute__((address_space(1))) unsigned int*)(uintptr_t)g,
      (__attribute__((address_space(3))) unsigned int*)(unsigned int)(uintptr_t)lds_p,
      16, 0, 0);
}

#define WAITV8 asm volatile("s_waitcnt vmcnt(8)" ::: "memory")
#define WAITV0 asm volatile("s_waitcnt vmcnt(0)" ::: "memory")
#define WAITL0 asm volatile("s_waitcnt lgkmcnt(0)" ::: "memory")
#define SCHEDB __builtin_amdgcn_sched_barrier(0)
#define BAR    __builtin_amdgcn_s_barrier()

// Stage one K-tile: A[128][64] + B[128][64] f16, source-pre-swizzled so that
// LDS[row][slot] = G[row][slot ^ (row&7)]  (slot = 16B unit). gll dest linear.
__device__ __forceinline__ void stage_tile(const unsigned short* gA, const unsigned short* gB,
                                           size_t sA, size_t sB,
                                           int k0, unsigned short* buf, int w, int lane) {
  int rl = lane >> 3;                      // row-within-8  == row&7
  int sg = ((lane & 7) ^ rl) << 3;         // swizzled source slot, in elements
#pragma unroll
  for (int j = 0; j < 4; j++) {
    int c = w * 4 + j;                     // chunk 0..15 (8 rows each)
    int row = c * 8 + rl;
    gll16(gA + (size_t)row * sA + k0 + sg, buf + c * 512);
    gll16(gB + (size_t)row * sB + k0 + sg, buf + 8192 + c * 512);
  }
}

// Read all MFMA fragments of the current K-tile (swizzled addressing).
__device__ __forceinline__ void load_frags(const unsigned short* buf, int wr, int wc,
                                           int l15, int l4, f16x8 af[4][2], f16x8 bf[4][2]) {
  const unsigned short* bA = buf;
  const unsigned short* bB = buf + 8192;
#pragma unroll
  for (int m = 0; m < 4; m++) {
    int row = wr * 64 + m * 16 + l15, rs = row & 7;
    af[m][0] = *(const f16x8*)(bA + row * 64 + ((l4 ^ rs) << 3));
    af[m][1] = *(const f16x8*)(bA + row * 64 + (((4 + l4) ^ rs) << 3));
  }
#pragma unroll
  for (int n = 0; n < 4; n++) {
    int row = wc * 64 + n * 16 + l15, rs = row & 7;
    bf[n][0] = *(const f16x8*)(bB + row * 64 + ((l4 ^ rs) << 3));
    bf[n][1] = *(const f16x8*)(bB + row * 64 + (((4 + l4) ^ rs) << 3));
  }
}

__device__ __forceinline__ void mfma_tile(f16x8 af[4][2], f16x8 bf[4][2], f32x4 acc[4][4]) {
#pragma unroll
  for (int m = 0; m < 4; m++)
#pragma unroll
    for (int n = 0; n < 4; n++) {
      acc[m][n] = __builtin_amdgcn_mfma_f32_16x16x32_f16(af[m][0], bf[n][0], acc[m][n], 0, 0, 0);
      acc[m][n] = __builtin_amdgcn_mfma_f32_16x16x32_f16(af[m][1], bf[n][1], acc[m][n], 0, 0, 0);
    }
}

// Deep-pipelined K-loop: tile t in lds[t&1]; stage t+2 into the just-freed buffer;
// counted vmcnt(8) keeps t+2's loads in flight across barriers. nt must be even.
__device__ __forceinline__ void gemm_core(const unsigned short* gA, const unsigned short* gB,
                                          size_t sA, size_t sB,
                                          unsigned short* lds0, unsigned short* lds1, int nt,
                                          int w, int lane, int wr, int wc, int l15, int l4,
                                          f32x4 acc[4][4]) {
  stage_tile(gA, gB, sA, sB, 0, lds0, w, lane);
  stage_tile(gA, gB, sA, sB, 64, lds1, w, lane);
  WAITV8; SCHEDB; BAR;
  f16x8 af[4][2], bf[4][2];
  for (int t = 0; t < nt; t += 2) {
    // even sub-iter: buffer lds0, tile t
    load_frags(lds0, wr, wc, l15, l4, af, bf);
    WAITL0; SCHEDB; BAR;                       // all waves done reading lds0
    if (t + 2 < nt) stage_tile(gA, gB, sA, sB, (t + 2) * 64, lds0, w, lane);
    __builtin_amdgcn_s_setprio(1);
    mfma_tile(af, bf, acc);
    __builtin_amdgcn_s_setprio(0);
    if (t + 2 < nt) { WAITV8; } else { WAITV0; }   // tile t+1 landed
    SCHEDB; BAR;
    // odd sub-iter: buffer lds1, tile t+1
    load_frags(lds1, wr, wc, l15, l4, af, bf);
    WAITL0; SCHEDB; BAR;
    if (t + 3 < nt) stage_tile(gA, gB, sA, sB, (t + 3) * 64, lds1, w, lane);
    __builtin_amdgcn_s_setprio(1);
    mfma_tile(af, bf, acc);
    __builtin_amdgcn_s_setprio(0);
    if (t + 3 < nt) { WAITV8; } else { WAITV0; }
    SCHEDB; BAR;
  }
}

// ---- kernel 1: x f32 -> f16 ----
__global__ __launch_bounds__(256) void cvt_x(const float* __restrict__ x,
                                             unsigned short* __restrict__ o, int n8) {
  int i = blockIdx.x * 256 + threadIdx.x;
  if (i >= n8) return;
  const float4* p = (const float4*)x + (size_t)i * 2;
  float4 a = p[0], b = p[1];
  u16x8 r;
  r[0] = f2h(a.x); r[1] = f2h(a.y); r[2] = f2h(a.z); r[3] = f2h(a.w);
  r[4] = f2h(b.x); r[5] = f2h(b.y); r[6] = f2h(b.z); r[7] = f2h(b.w);
  *((u16x8*)o + i) = r;
}

// ---- kernel 2: W [k][n] f32 -> Wt [n][k] f16 ----
__global__ __launch_bounds__(256) void cvt_w(const float* __restrict__ W0,
                                             const float* __restrict__ W1,
                                             const float* __restrict__ W2,
                                             unsigned short* __restrict__ out) {
  __shared__ float t[32][33];
  int z = blockIdx.z;
  const float* W = (z == 0) ? W0 : (z == 1 ? W1 : W2);
  unsigned short* o = out + (size_t)z * 1024 * 1024;
  int c0 = blockIdx.x * 32, r0 = blockIdx.y * 32;
  int tx = threadIdx.x, ty = threadIdx.y;
  for (int i = 0; i < 4; i++)
    t[ty + 8 * i][tx] = W[(size_t)(r0 + ty + 8 * i) * 1024 + c0 + tx];
  __syncthreads();
  for (int i = 0; i < 4; i++)
    o[(size_t)(c0 + ty + 8 * i) * 1024 + r0 + tx] = f2h(t[tx][ty + 8 * i]);
}

// ---- kernel 3: fused QKV GEMM (N=3072), deep pipeline; V written transposed+coalesced ----
__global__ __launch_bounds__(256) void qkv_gemm(const unsigned short* __restrict__ xb,
                                                const unsigned short* __restrict__ wt,
                                                const float* __restrict__ b0,
                                                const float* __restrict__ b1,
                                                const float* __restrict__ b2,
                                                unsigned short* __restrict__ Qp,
                                                unsigned short* __restrict__ Kp,
                                                unsigned short* __restrict__ vtp) {
  __shared__ unsigned short lds[2][16384];   // [buf][A 8192 | B 8192]
  int m0 = blockIdx.x * 128;
  int n0 = blockIdx.y * 128;
  int z = n0 >> 10, nz = n0 & 1023;
  const unsigned short* gA = xb + (size_t)m0 * 1024;
  const unsigned short* gB = wt + (size_t)z * 1048576 + (size_t)nz * 1024;
  const float* bias = (z == 0) ? b0 : (z == 1 ? b1 : b2);
  int tid = threadIdx.x, lane = tid & 63, w = tid >> 6;
  int wr = w >> 1, wc = w & 1, l15 = lane & 15, l4 = lane >> 4;
  f32x4 acc[4][4] = {};
  gemm_core(gA, gB, 1024, 1024, &lds[0][0], &lds[1][0], 16, w, lane, wr, wc, l15, l4, acc);

  if (z < 2) {
    unsigned short* O = (z == 0) ? Qp : Kp;
#pragma unroll
    for (int m = 0; m < 4; m++)
#pragma unroll
      for (int n = 0; n < 4; n++) {
        int cl = wc * 64 + n * 16 + l15;
        float bv = bias[nz + cl];
#pragma unroll
        for (int r = 0; r < 4; r++) {
          int row = m0 + wr * 64 + m * 16 + l4 * 4 + r;
          O[(size_t)row * 1024 + nz + cl] = f2h(acc[m][n][r] + bv);
        }
      }
  } else {
    // V: transpose 128x128 tile in LDS, then coalesced store to vtp[b][d][s]
    unsigned short* T = &lds[0][0];          // 128 x 136 f16 = 34 KB (fits in 64 KB)
#pragma unroll
    for (int m = 0; m < 4; m++)
#pragma unroll
      for (int n = 0; n < 4; n++) {
        int cl = wc * 64 + n * 16 + l15;     // d-local
        float bv = bias[nz + cl];
#pragma unroll
        for (int r = 0; r < 4; r++) {
          int rl = wr * 64 + m * 16 + l4 * 4 + r;   // s-local
          T[cl * 136 + rl] = f2h(acc[m][n][r] + bv);
        }
      }
    __syncthreads();
    int bidx = m0 >> 11, s0 = m0 & 2047;
#pragma unroll
    for (int i = 0; i < 8; i++) {
      int d = w * 32 + i * 4 + (lane >> 4);
      int ch = lane & 15;
      u16x8 v = *(const u16x8*)(T + d * 136 + ch * 8);
      *(u16x8*)(vtp + ((size_t)bidx * 1024 + nz + d) * 2048 + s0 + ch * 8) = v;
    }
  }
}

// ---- kernel 4: scores = Q K^T * SCALE, causal mask, triangular-packed f32 ----
__global__ __launch_bounds__(256) void qk_scores(const unsigned short* __restrict__ Q,
                                                 const unsigned short* __restrict__ Kb,
                                                 float* __restrict__ sc) {
  __shared__ unsigned short lds[2][16384];
  int b = blockIdx.y;
  int i = blockIdx.x;
  int qt = (int)((sqrtf(8.f * i + 1.f) - 1.f) * 0.5f);
  while ((qt + 1) * (qt + 2) / 2 <= i) qt++;
  while (qt * (qt + 1) / 2 > i) qt--;
  int kt = i - qt * (qt + 1) / 2;
  int Wspan = (qt + 1) << 7;
  const unsigned short* gA = Q  + ((size_t)b * 2048 + qt * 128) * 1024;
  const unsigned short* gB = Kb + ((size_t)b * 2048 + kt * 128) * 1024;
  float* outp = sc + (size_t)b * P_ELEMS + (size_t)16384 * (qt * (qt + 1) / 2);
  int tid = threadIdx.x, lane = tid & 63, w = tid >> 6;
  int wr = w >> 1, wc = w & 1, l15 = lane & 15, l4 = lane >> 4;
  f32x4 acc[4][4] = {};
  gemm_core(gA, gB, 1024, 1024, &lds[0][0], &lds[1][0], 16, w, lane, wr, wc, l15, l4, acc);
#pragma unroll
  for (int m = 0; m < 4; m++)
#pragma unroll
    for (int n = 0; n < 4; n++) {
      int cl = wc * 64 + n * 16 + l15;
      int kv = kt * 128 + cl;
#pragma unroll
      for (int r = 0; r < 4; r++) {
        int rl = wr * 64 + m * 16 + l4 * 4 + r;
        int srow = qt * 128 + rl;
        float v = acc[m][n][r] * SCALE;
        if (kv > srow) v = -1e30f;
        outp[(size_t)rl * Wspan + kv] = v;
      }
    }
}

// ---- kernel 5: row softmax (row in registers), write f16 P packed ----
__global__ __launch_bounds__(256) void softmax_row(const float* __restrict__ sc,
                                                   unsigned short* __restrict__ pb) {
  __shared__ float redm[4];
  __shared__ float reds[4];
  int srow = blockIdx.x;
  int b = srow >> 11, sl = srow & 2047;
  int qt = sl >> 7;
  int Wspan = (qt + 1) << 7;
  size_t rb = (size_t)b * P_ELEMS + (size_t)16384 * (qt * (qt + 1) / 2) + (size_t)(sl & 127) * Wspan;
  const float4* src = (const float4*)(sc + rb);
  int nv = Wspan >> 2;
  int t = threadIdx.x, lane = t & 63, w = t >> 6;
  bool h0 = t < nv, h1 = (t + 256) < nv;
  float4 v0 = make_float4(0, 0, 0, 0), v1 = make_float4(0, 0, 0, 0);
  if (h0) v0 = src[t];
  if (h1) v1 = src[t + 256];
  float mx = -1e30f;
  if (h0) mx = fmaxf(fmaxf(v0.x, v0.y), fmaxf(v0.z, v0.w));
  if (h1) mx = fmaxf(mx, fmaxf(fmaxf(v1.x, v1.y), fmaxf(v1.z, v1.w)));
  for (int off = 1; off < 64; off <<= 1) mx = fmaxf(mx, __shfl_xor(mx, off, 64));
  if (lane == 0) redm[w] = mx;
  __syncthreads();
  mx = fmaxf(fmaxf(redm[0], redm[1]), fmaxf(redm[2], redm[3]));
  float s = 0.f;
  float4 e0, e1;
  if (h0) {
    e0.x = __expf(v0.x - mx); e0.y = __expf(v0.y - mx);
    e0.z = __expf(v0.z - mx); e0.w = __expf(v0.w - mx);
    s += e0.x + e0.y + e0.z + e0.w;
  }
  if (h1) {
    e1.x = __expf(v1.x - mx); e1.y = __expf(v1.y - mx);
    e1.z = __expf(v1.z - mx); e1.w = __expf(v1.w - mx);
    s += e1.x + e1.y + e1.z + e1.w;
  }
  for (int off = 1; off < 64; off <<= 1) s += __shfl_xor(s, off, 64);
  if (lane == 0) reds[w] = s;
  __syncthreads();
  s = reds[0] + reds[1] + reds[2] + reds[3];
  float inv = 1.f / s;
  u16x4* dst = (u16x4*)(pb + rb);
  if (h0) {
    u16x4 o;
    o[0] = f2h(e0.x * inv); o[1] = f2h(e0.y * inv);
    o[2] = f2h(e0.z * inv); o[3] = f2h(e0.w * inv);
    dst[t] = o;
  }
  if (h1) {
    u16x4 o;
    o[0] = f2h(e1.x * inv); o[1] = f2h(e1.y * inv);
    o[2] = f2h(e1.z * inv); o[3] = f2h(e1.w * inv);
    dst[t + 256] = o;
  }
}

// ---- kernel 6: O = P Vt — paired tiles (qt=p and qt=15-p): 34 K-iters per block ----
__global__ __launch_bounds__(256) void pv_gemm(const unsigned short* __restrict__ pb,
                                               const unsigned short* __restrict__ vtp,
                                               float* __restrict__ outp) {
  __shared__ unsigned short lds[2][16384];
  int p = blockIdx.x;        // 0..7
  int n0 = blockIdx.y * 128;
  int b = blockIdx.z;
  int tid = threadIdx.x, lane = tid & 63, w = tid >> 6;
  int wr = w >> 1, wc = w & 1, l15 = lane & 15, l4 = lane >> 4;
  const unsigned short* gB = vtp + (size_t)b * 1024 * 2048 + (size_t)n0 * 2048;
#pragma unroll
  for (int which = 0; which < 2; which++) {
    int qt = which ? (15 - p) : p;
    int Wspan = (qt + 1) << 7;
    const unsigned short* gA = pb + (size_t)b * P_ELEMS + (size_t)16384 * (qt * (qt + 1) / 2);
    float* O = outp + ((size_t)b * 2048 + qt * 128) * 1024;
    f32x4 acc[4][4] = {};
    gemm_core(gA, gB, Wspan, 2048, &lds[0][0], &lds[1][0], 2 * (qt + 1),
              w, lane, wr, wc, l15, l4, acc);
#pragma unroll
    for (int m = 0; m < 4; m++)
#pragma unroll
      for (int n = 0; n < 4; n++) {
        int cl = n0 + wc * 64 + n * 16 + l15;
#pragma unroll
        for (int r = 0; r < 4; r++) {
          int rl = wr * 64 + m * 16 + l4 * 4 + r;
          O[(size_t)rl * 1024 + cl] = acc[m][n][r];
        }
      }
  }
}

extern "C" void kernel_launch(void* const* d_in, const int* in_sizes, int n_in,
                              void* d_out, int out_size, void* d_ws, size_t ws_size,
                              hipStream_t stream) {
  const float* x  = (const float*)d_in[0];
  const float* Wq = (const float*)d_in[1];
  const float* bq = (const float*)d_in[2];
  const float* Wk = (const float*)d_in[3];
  const float* bk = (const float*)d_in[4];
  const float* Wv = (const float*)d_in[5];
  const float* bv = (const float*)d_in[6];
  float* out = (float*)d_out;

  unsigned short* ws  = (unsigned short*)d_ws;
  unsigned short* wt  = ws;                          // 3,145,728 ushorts
  unsigned short* Qp  = ws + 3145728;                // 8,388,608
  unsigned short* Kp  = ws + 11534336;               // 8,388,608
  unsigned short* vtp = ws + 19922944;               // 8,388,608 (V^T [b][d][s])
  float* sc           = (float*)(ws + 28311552);     // 4*P_ELEMS f32 (packed tri)
  unsigned short* pb  = ws + 46137344;               // 4*P_ELEMS f16 (packed tri)
  unsigned short* xb  = (unsigned short*)d_out;      // x f16 scratch (overwritten by pv)

  cvt_x<<<4096, 256, 0, stream>>>(x, xb, 1048576);
  cvt_w<<<dim3(32, 32, 3), dim3(32, 8), 0, stream>>>(Wq, Wk, Wv, wt);
  qkv_gemm<<<dim3(64, 24), 256, 0, stream>>>(xb, wt, bq, bk, bv, Qp, Kp, vtp);
  qk_scores<<<dim3(136, 4), 256, 0, stream>>>(Qp, Kp, sc);
  softmax_row<<<8192, 256, 0, stream>>>(sc, pb);
  pv_gemm<<<dim3(8, 8, 4), 256, 0, stream>>>(pb, vtp, out);
}